// Round 1
// baseline (5987.775 us; speedup 1.0000x reference)
//
#include <hip/hip_runtime.h>

typedef _Float16 f16x8 __attribute__((ext_vector_type(8)));
typedef float f32x4 __attribute__((ext_vector_type(4)));

#define VOCAB 128
#define EMB 512
#define HID 1024
#define BATCH 256
#define TSEQ 256

// ---- workspace layout (element offsets) ----
// f16 region (from start of ws)
#define WIH0_HI 0
#define WIH0_LO (WIH0_HI + HID*EMB)
#define WHH0_HI (WIH0_LO + HID*EMB)
#define WHH0_LO (WHH0_HI + HID*HID)
#define WIH1_HI (WHH0_LO + HID*HID)
#define WIH1_LO (WIH1_HI + HID*HID)
#define WHH1_HI (WIH1_LO + HID*HID)
#define WHH1_LO (WHH1_HI + HID*HID)
#define WOUT_HI (WHH1_LO + HID*HID)
#define WOUT_LO (WOUT_HI + VOCAB*HID)
#define H0_BUF  (WOUT_LO + VOCAB*HID)      // 2 buffers of BATCH*HID f16
#define H1_BUF  (H0_BUF + 2*BATCH*HID)     // 2 buffers of BATCH*HID f16
#define F16_TOTAL (H1_BUF + 2*BATCH*HID)
// f32 region (starts at byte offset F16_TOTAL*2, 16B aligned)
#define PRE0_BUF 0                          // 2 buffers of BATCH*HID f32
#define PRE1_BUF (2*BATCH*HID)

// ---- prep kernels ----
__global__ void split_w(const float* __restrict__ src, _Float16* __restrict__ hi,
                        _Float16* __restrict__ lo, int n) {
    int i = blockIdx.x * blockDim.x + threadIdx.x;
    if (i < n) {
        float v = src[i];
        _Float16 h = (_Float16)v;
        hi[i] = h;
        lo[i] = (_Float16)(v - (float)h);
    }
}

__global__ void zero_h(_Float16* __restrict__ p, int n) {
    int i = blockIdx.x * blockDim.x + threadIdx.x;
    if (i < n) p[i] = (_Float16)0.f;
}

// ---- the per-step pipelined kernel ----
// grid = 256 blocks: op = blockIdx.x>>6 (0:G0 1:R0 2:G1 3:R1), tile = blockIdx.x&63
// Each block computes a 64x64 tile of a [256,1024] output; 4 waves of 32x32.
__global__ __launch_bounds__(256) void rnn_step(
    int s,
    const int* __restrict__ tokens, const float* __restrict__ emb,
    const float* __restrict__ b_ih0, const float* __restrict__ b_hh0,
    const float* __restrict__ b_ih1, const float* __restrict__ b_hh1,
    _Float16* __restrict__ wsh, float* __restrict__ wsf)
{
    const int op   = blockIdx.x >> 6;
    const int tile = blockIdx.x & 63;
    const int m0 = (tile >> 4) * 64;   // 4 row-tiles over 256
    const int n0 = (tile & 15) * 64;   // 16 col-tiles over 1024

    int K;
    const _Float16 *A16 = nullptr, *Bhi, *Blo;
    const float *bias, *preadd = nullptr;
    float* out32 = nullptr;
    _Float16* out16 = nullptr;
    bool gather = false;

    switch (op) {
    case 0: // G0: pre0_t = embed(tokens[:,s]) @ W_ih0^T + b_ih0
        if (s >= TSEQ) return;
        gather = true; K = EMB;
        Bhi = wsh + WIH0_HI; Blo = wsh + WIH0_LO; bias = b_ih0;
        out32 = wsf + PRE0_BUF + (size_t)(s & 1) * (BATCH * HID);
        break;
    case 1: // R0: h0_{s-1} = tanh(pre0_{s-1} + h0_{s-2} @ W_hh0^T + b_hh0)
        if (s < 1 || s > TSEQ) return;
        A16 = wsh + H0_BUF + (size_t)(s & 1) * (BATCH * HID); K = HID;
        Bhi = wsh + WHH0_HI; Blo = wsh + WHH0_LO; bias = b_hh0;
        preadd = wsf + PRE0_BUF + (size_t)((s - 1) & 1) * (BATCH * HID);
        out16 = wsh + H0_BUF + (size_t)((s - 1) & 1) * (BATCH * HID);
        break;
    case 2: // G1: pre1_{s-2} = h0_{s-2} @ W_ih1^T + b_ih1
        if (s < 2 || s > TSEQ + 1) return;
        A16 = wsh + H0_BUF + (size_t)(s & 1) * (BATCH * HID); K = HID;
        Bhi = wsh + WIH1_HI; Blo = wsh + WIH1_LO; bias = b_ih1;
        out32 = wsf + PRE1_BUF + (size_t)(s & 1) * (BATCH * HID);
        break;
    default: // R1: h1_{s-3} = tanh(pre1_{s-3} + h1_{s-4} @ W_hh1^T + b_hh1)
        if (s < 3 || s > TSEQ + 2) return;
        A16 = wsh + H1_BUF + (size_t)(s & 1) * (BATCH * HID); K = HID;
        Bhi = wsh + WHH1_HI; Blo = wsh + WHH1_LO; bias = b_hh1;
        preadd = wsf + PRE1_BUF + (size_t)((s - 1) & 1) * (BATCH * HID);
        out16 = wsh + H1_BUF + (size_t)((s - 1) & 1) * (BATCH * HID);
        break;
    }

    __shared__ _Float16 At[64 * 40];
    __shared__ _Float16 Bth[64 * 40];
    __shared__ _Float16 Btl[64 * 40];

    const int tid  = threadIdx.x;
    const int lane = tid & 63;
    const int wv   = tid >> 6;
    const int wm   = wv & 1;    // wave row (0..1) -> 32 rows each
    const int wn   = wv >> 1;   // wave col (0..1) -> 32 cols each
    const int srow = tid >> 2;          // staging row 0..63
    const int skp  = (tid & 3) * 8;     // staging k-offset {0,8,16,24}

    f32x4 acc[2][2] = {};

    int tok = 0;
    if (gather) tok = tokens[(m0 + srow) * TSEQ + s];

    for (int k0 = 0; k0 < K; k0 += 32) {
        // ---- stage A tile [64 x 32] ----
        if (gather) {
            const float* p = emb + (size_t)tok * EMB + k0 + skp;
            float4 u0 = *(const float4*)p;
            float4 u1 = *(const float4*)(p + 4);
            f16x8 a;
            a[0] = (_Float16)u0.x; a[1] = (_Float16)u0.y;
            a[2] = (_Float16)u0.z; a[3] = (_Float16)u0.w;
            a[4] = (_Float16)u1.x; a[5] = (_Float16)u1.y;
            a[6] = (_Float16)u1.z; a[7] = (_Float16)u1.w;
            *(f16x8*)&At[srow * 40 + skp] = a;
        } else {
            *(f16x8*)&At[srow * 40 + skp] =
                *(const f16x8*)(A16 + (size_t)(m0 + srow) * HID + k0 + skp);
        }
        // ---- stage B tiles (weight rows n0..n0+63, hi and lo) ----
        *(f16x8*)&Bth[srow * 40 + skp] =
            *(const f16x8*)(Bhi + (size_t)(n0 + srow) * K + k0 + skp);
        *(f16x8*)&Btl[srow * 40 + skp] =
            *(const f16x8*)(Blo + (size_t)(n0 + srow) * K + k0 + skp);
        __syncthreads();

        // ---- MFMA: each wave 32x32, 2x2 frags, 2 passes (hi, lo) ----
        const int lr = lane & 15;
        const int lk = (lane >> 4) * 8;
        f16x8 a0  = *(const f16x8*)&At [(wm * 32 +      lr) * 40 + lk];
        f16x8 a1  = *(const f16x8*)&At [(wm * 32 + 16 + lr) * 40 + lk];
        f16x8 bh0 = *(const f16x8*)&Bth[(wn * 32 +      lr) * 40 + lk];
        f16x8 bh1 = *(const f16x8*)&Bth[(wn * 32 + 16 + lr) * 40 + lk];
        f16x8 bl0 = *(const f16x8*)&Btl[(wn * 32 +      lr) * 40 + lk];
        f16x8 bl1 = *(const f16x8*)&Btl[(wn * 32 + 16 + lr) * 40 + lk];

        acc[0][0] = __builtin_amdgcn_mfma_f32_16x16x32_f16(a0, bh0, acc[0][0], 0, 0, 0);
        acc[0][1] = __builtin_amdgcn_mfma_f32_16x16x32_f16(a0, bh1, acc[0][1], 0, 0, 0);
        acc[1][0] = __builtin_amdgcn_mfma_f32_16x16x32_f16(a1, bh0, acc[1][0], 0, 0, 0);
        acc[1][1] = __builtin_amdgcn_mfma_f32_16x16x32_f16(a1, bh1, acc[1][1], 0, 0, 0);
        acc[0][0] = __builtin_amdgcn_mfma_f32_16x16x32_f16(a0, bl0, acc[0][0], 0, 0, 0);
        acc[0][1] = __builtin_amdgcn_mfma_f32_16x16x32_f16(a0, bl1, acc[0][1], 0, 0, 0);
        acc[1][0] = __builtin_amdgcn_mfma_f32_16x16x32_f16(a1, bl0, acc[1][0], 0, 0, 0);
        acc[1][1] = __builtin_amdgcn_mfma_f32_16x16x32_f16(a1, bl1, acc[1][1], 0, 0, 0);
        __syncthreads();
    }

    // ---- epilogue: C row=(lane>>4)*4+reg, col=lane&15 ----
    const int erow = m0 + wm * 32 + (lane >> 4) * 4;
    const int ecol = n0 + wn * 32 + (lane & 15);
    for (int i = 0; i < 2; ++i) {
        for (int j = 0; j < 2; ++j) {
            const int cc = ecol + j * 16;
            const float bv = bias[cc];
            for (int r = 0; r < 4; ++r) {
                const int rr = erow + i * 16 + r;
                float v = acc[i][j][r] + bv;
                if (out16) {
                    v = tanhf(v + preadd[(size_t)rr * HID + cc]);
                    out16[(size_t)rr * HID + cc] = (_Float16)v;
                } else {
                    out32[(size_t)rr * HID + cc] = v;
                }
            }
        }
    }
}

// ---- head: out[256,128] = h1_final @ W_out^T + b_out ----
__global__ __launch_bounds__(256) void head_kernel(
    const _Float16* __restrict__ A16,
    const _Float16* __restrict__ Bhi, const _Float16* __restrict__ Blo,
    const float* __restrict__ bias, float* __restrict__ out)
{
    const int m0 = (blockIdx.x >> 1) * 64;  // 4 row tiles
    const int n0 = (blockIdx.x & 1) * 64;   // 2 col tiles
    const int K = HID;

    __shared__ _Float16 At[64 * 40];
    __shared__ _Float16 Bth[64 * 40];
    __shared__ _Float16 Btl[64 * 40];

    const int tid  = threadIdx.x;
    const int lane = tid & 63;
    const int wv   = tid >> 6;
    const int wm   = wv & 1;
    const int wn   = wv >> 1;
    const int srow = tid >> 2;
    const int skp  = (tid & 3) * 8;

    f32x4 acc[2][2] = {};

    for (int k0 = 0; k0 < K; k0 += 32) {
        *(f16x8*)&At[srow * 40 + skp] =
            *(const f16x8*)(A16 + (size_t)(m0 + srow) * HID + k0 + skp);
        *(f16x8*)&Bth[srow * 40 + skp] =
            *(const f16x8*)(Bhi + (size_t)(n0 + srow) * K + k0 + skp);
        *(f16x8*)&Btl[srow * 40 + skp] =
            *(const f16x8*)(Blo + (size_t)(n0 + srow) * K + k0 + skp);
        __syncthreads();

        const int lr = lane & 15;
        const int lk = (lane >> 4) * 8;
        f16x8 a0  = *(const f16x8*)&At [(wm * 32 +      lr) * 40 + lk];
        f16x8 a1  = *(const f16x8*)&At [(wm * 32 + 16 + lr) * 40 + lk];
        f16x8 bh0 = *(const f16x8*)&Bth[(wn * 32 +      lr) * 40 + lk];
        f16x8 bh1 = *(const f16x8*)&Bth[(wn * 32 + 16 + lr) * 40 + lk];
        f16x8 bl0 = *(const f16x8*)&Btl[(wn * 32 +      lr) * 40 + lk];
        f16x8 bl1 = *(const f16x8*)&Btl[(wn * 32 + 16 + lr) * 40 + lk];

        acc[0][0] = __builtin_amdgcn_mfma_f32_16x16x32_f16(a0, bh0, acc[0][0], 0, 0, 0);
        acc[0][1] = __builtin_amdgcn_mfma_f32_16x16x32_f16(a0, bh1, acc[0][1], 0, 0, 0);
        acc[1][0] = __builtin_amdgcn_mfma_f32_16x16x32_f16(a1, bh0, acc[1][0], 0, 0, 0);
        acc[1][1] = __builtin_amdgcn_mfma_f32_16x16x32_f16(a1, bh1, acc[1][1], 0, 0, 0);
        acc[0][0] = __builtin_amdgcn_mfma_f32_16x16x32_f16(a0, bl0, acc[0][0], 0, 0, 0);
        acc[0][1] = __builtin_amdgcn_mfma_f32_16x16x32_f16(a0, bl1, acc[0][1], 0, 0, 0);
        acc[1][0] = __builtin_amdgcn_mfma_f32_16x16x32_f16(a1, bl0, acc[1][0], 0, 0, 0);
        acc[1][1] = __builtin_amdgcn_mfma_f32_16x16x32_f16(a1, bl1, acc[1][1], 0, 0, 0);
        __syncthreads();
    }

    const int erow = m0 + wm * 32 + (lane >> 4) * 4;
    const int ecol = n0 + wn * 32 + (lane & 15);
    for (int i = 0; i < 2; ++i) {
        for (int j = 0; j < 2; ++j) {
            const int cc = ecol + j * 16;
            const float bv = bias[cc];
            for (int r = 0; r < 4; ++r) {
                const int rr = erow + i * 16 + r;
                out[(size_t)rr * VOCAB + cc] = acc[i][j][r] + bv;
            }
        }
    }
}

extern "C" void kernel_launch(void* const* d_in, const int* in_sizes, int n_in,
                              void* d_out, int out_size, void* d_ws, size_t ws_size,
                              hipStream_t stream) {
    const int*   tokens = (const int*)  d_in[0];
    const float* emb    = (const float*)d_in[1];
    const float* W_ih0  = (const float*)d_in[2];
    const float* W_hh0  = (const float*)d_in[3];
    const float* b_ih0  = (const float*)d_in[4];
    const float* b_hh0  = (const float*)d_in[5];
    const float* W_ih1  = (const float*)d_in[6];
    const float* W_hh1  = (const float*)d_in[7];
    const float* b_ih1  = (const float*)d_in[8];
    const float* b_hh1  = (const float*)d_in[9];
    const float* W_out  = (const float*)d_in[10];
    const float* b_out  = (const float*)d_in[11];
    float* out = (float*)d_out;

    _Float16* wsh = (_Float16*)d_ws;
    float*    wsf = (float*)((char*)d_ws + (size_t)F16_TOTAL * 2);

    // weight hi/lo split (fp16 2-pass decomposition)
    split_w<<<(HID*EMB   + 255) / 256, 256, 0, stream>>>(W_ih0, wsh + WIH0_HI, wsh + WIH0_LO, HID*EMB);
    split_w<<<(HID*HID   + 255) / 256, 256, 0, stream>>>(W_hh0, wsh + WHH0_HI, wsh + WHH0_LO, HID*HID);
    split_w<<<(HID*HID   + 255) / 256, 256, 0, stream>>>(W_ih1, wsh + WIH1_HI, wsh + WIH1_LO, HID*HID);
    split_w<<<(HID*HID   + 255) / 256, 256, 0, stream>>>(W_hh1, wsh + WHH1_HI, wsh + WHH1_LO, HID*HID);
    split_w<<<(VOCAB*HID + 255) / 256, 256, 0, stream>>>(W_out, wsh + WOUT_HI, wsh + WOUT_LO, VOCAB*HID);
    // zero initial hidden states (h0[2] and h1[2] are contiguous)
    zero_h<<<(4*BATCH*HID + 255) / 256, 256, 0, stream>>>(wsh + H0_BUF, 4*BATCH*HID);

    // software-pipelined steps: G0(s), R0(s-1), G1(s-2), R1(s-3)
    for (int s = 0; s <= TSEQ + 2; ++s) {
        rnn_step<<<256, 256, 0, stream>>>(s, tokens, emb, b_ih0, b_hh0, b_ih1, b_hh1, wsh, wsf);
    }

    // final h1 is in buffer ((TSEQ+2-1)&1) = 1
    head_kernel<<<8, 256, 0, stream>>>(wsh + H1_BUF + (size_t)BATCH * HID,
                                       wsh + WOUT_HI, wsh + WOUT_LO, b_out, out);
}

// Round 3
// 5973.455 us; speedup vs baseline: 1.0024x; 1.0024x over previous
//
#include <hip/hip_runtime.h>
#include <hip/hip_cooperative_groups.h>

namespace cg = cooperative_groups;

typedef _Float16 f16x8 __attribute__((ext_vector_type(8)));
typedef float f32x4 __attribute__((ext_vector_type(4)));

#define VOCAB 128
#define EMB 512
#define HID 1024
#define BATCH 256
#define TSEQ 256

// ======================= persistent-kernel ws layout =======================
// f16 region: h0[2][256*1024], h1[2][256*1024]
#define P_H0_OFF 0
#define P_H1_OFF (2 * BATCH * HID)
#define P_F16_TOT (4 * BATCH * HID)
// f32 region (after f16): PROJ[128*1024], pre1[2][256*1024]
#define P_PROJ_OFF 0
#define P_PRE1_OFF (VOCAB * HID)

#define PGRID 192
#define PTHREADS (PGRID * 256)

__device__ __forceinline__ f32x4 mfma16(f16x8 a, f16x8 b, f32x4 c) {
    return __builtin_amdgcn_mfma_f32_16x16x32_f16(a, b, c, 0, 0, 0);
}

__global__ __launch_bounds__(256, 1) void rnn_persist(
    const int* __restrict__ tokens, const float* __restrict__ emb,
    const float* __restrict__ Wih0, const float* __restrict__ Whh0,
    const float* __restrict__ b_ih0, const float* __restrict__ b_hh0,
    const float* __restrict__ Wih1, const float* __restrict__ Whh1,
    const float* __restrict__ b_ih1, const float* __restrict__ b_hh1,
    const float* __restrict__ Wout, const float* __restrict__ b_out,
    _Float16* __restrict__ wsh, float* __restrict__ wsf,
    float* __restrict__ out)
{
    cg::grid_group grid = cg::this_grid();
    const int blk = blockIdx.x, tid = threadIdx.x;
    const int lane = tid & 63, wv = tid >> 6;

    _Float16* h0 = wsh + P_H0_OFF;
    _Float16* h1 = wsh + P_H1_OFF;
    float* PROJ = wsf + P_PROJ_OFF;
    float* pre1 = wsf + P_PRE1_OFF;

    // ---- init: zero both h0 and h1 ping-pong buffers ----
    {
        const int gt = blk * 256 + tid;
        f16x8 z = {};
        for (int i = gt; i < P_F16_TOT / 8; i += PTHREADS)
            *(f16x8*)(wsh + (size_t)i * 8) = z;
    }
    // ---- init: PROJ[v][n] = emb[v,:] . Wih0[n,:] + b_ih0[n]  (f32, once) ----
    {
        const int gt = blk * 256 + tid;
        for (int o = gt; o < VOCAB * HID; o += PTHREADS) {
            const int v = o >> 10, n = o & (HID - 1);
            const float* er = emb + (size_t)v * EMB;
            const float* wr = Wih0 + (size_t)n * EMB;
            float acc = 0.f;
            #pragma unroll 4
            for (int k = 0; k < EMB; k += 4) {
                float4 e = *(const float4*)(er + k);
                float4 w = *(const float4*)(wr + k);
                acc += e.x * w.x + e.y * w.y + e.z * w.z + e.w * w.w;
            }
            PROJ[o] = acc + b_ih0[n];
        }
    }

    // ---- roles: 0 = R0 (h0 recurrence), 1 = G1 (h0 -> pre1), 2 = R1 ----
    const int role = blk >> 6;            // 192 blocks -> 0,1,2
    const int n0 = (blk & 63) * 16;       // this block's 16 output columns
    const int mbase = wv * 64;            // this wave's 64 batch rows
    const int ar = lane & 15;             // fragment row/col index
    const int ak = (lane >> 4) * 8;       // fragment k offset
    const int er0 = mbase + (lane >> 4) * 4;

    // ---- register-resident weight slice: 16 cols x 1024 K, fp16 hi+lo ----
    f16x8 bh[32], bl[32];
    {
        const float* Wsrc = (role == 0) ? Whh0 : (role == 1) ? Wih1 : Whh1;
        const float* wp = Wsrc + (size_t)(n0 + ar) * HID + ak;
        #pragma unroll
        for (int kc = 0; kc < 32; ++kc) {
            float4 u0 = *(const float4*)(wp + kc * 32);
            float4 u1 = *(const float4*)(wp + kc * 32 + 4);
            float uf[8] = {u0.x, u0.y, u0.z, u0.w, u1.x, u1.y, u1.z, u1.w};
            f16x8 hh, ll;
            #pragma unroll
            for (int j = 0; j < 8; ++j) {
                _Float16 hv = (_Float16)uf[j];
                hh[j] = hv;
                ll[j] = (_Float16)(uf[j] - (float)hv);
            }
            bh[kc] = hh;
            bl[kc] = ll;
        }
    }
    const float bias = (role == 0) ? b_hh0[n0 + ar]
                     : (role == 1) ? b_ih1[n0 + ar]
                                   : b_hh1[n0 + ar];

    grid.sync();

    // ---- timestep loop; one grid sync per step ----
    // step s: R0 -> h0[s]; G1 -> pre1[s-1]; R1 -> h1[s-2]. buffers: parity of t.
    for (int s = 0; s < TSEQ + 2; ++s) {
        const bool active = (role == 0 && s < TSEQ) ||
                            (role == 1 && s >= 1 && s <= TSEQ) ||
                            (role == 2 && s >= 2);
        if (active) {
            const _Float16* Abuf =
                (role == 2 ? h1 : h0) + (size_t)((s + 1) & 1) * (BATCH * HID);
            const _Float16* Ab = Abuf + (size_t)(mbase + ar) * HID + ak;

            f32x4 acc[4] = {};
            #pragma unroll
            for (int kc = 0; kc < 32; ++kc) {
                #pragma unroll
                for (int mf = 0; mf < 4; ++mf) {
                    f16x8 a = *(const f16x8*)(Ab + (size_t)mf * (16 * HID) + kc * 32);
                    acc[mf] = mfma16(a, bh[kc], acc[mf]);
                    acc[mf] = mfma16(a, bl[kc], acc[mf]);
                }
            }

            const int cc = n0 + ar;
            if (role == 0) {
                _Float16* O = h0 + (size_t)(s & 1) * (BATCH * HID);
                #pragma unroll
                for (int mf = 0; mf < 4; ++mf) {
                    #pragma unroll
                    for (int r = 0; r < 4; ++r) {
                        const int rr = er0 + mf * 16 + r;
                        const int tok = tokens[rr * TSEQ + s];
                        float v = acc[mf][r] + PROJ[(size_t)tok * HID + cc] + bias;
                        O[(size_t)rr * HID + cc] = (_Float16)tanhf(v);
                    }
                }
            } else if (role == 1) {
                float* O = pre1 + (size_t)((s + 1) & 1) * (BATCH * HID);
                #pragma unroll
                for (int mf = 0; mf < 4; ++mf) {
                    #pragma unroll
                    for (int r = 0; r < 4; ++r) {
                        const int rr = er0 + mf * 16 + r;
                        O[(size_t)rr * HID + cc] = acc[mf][r] + bias;
                    }
                }
            } else {
                const float* P = pre1 + (size_t)(s & 1) * (BATCH * HID);
                _Float16* O = h1 + (size_t)(s & 1) * (BATCH * HID);
                #pragma unroll
                for (int mf = 0; mf < 4; ++mf) {
                    #pragma unroll
                    for (int r = 0; r < 4; ++r) {
                        const int rr = er0 + mf * 16 + r;
                        float v = acc[mf][r] + P[(size_t)rr * HID + cc] + bias;
                        O[(size_t)rr * HID + cc] = (_Float16)tanhf(v);
                    }
                }
            }
        }
        grid.sync();
    }

    // ---- head: out[m][n] = h1_final[m,:] . Wout[n,:] + b_out[n]  (f32) ----
    // final h1 = t=255 -> parity 1 buffer. Rows strided by grid size.
    if (tid < VOCAB) {
        for (int m = blk; m < BATCH; m += PGRID) {
            const _Float16* hrow = h1 + (size_t)(BATCH * HID) + (size_t)m * HID;
            const float* wrow = Wout + (size_t)tid * HID;
            float acc = 0.f;
            #pragma unroll 4
            for (int k = 0; k < HID; k += 8) {
                f16x8 hv = *(const f16x8*)(hrow + k);
                float4 w0 = *(const float4*)(wrow + k);
                float4 w1 = *(const float4*)(wrow + k + 4);
                acc += (float)hv[0] * w0.x + (float)hv[1] * w0.y +
                       (float)hv[2] * w0.z + (float)hv[3] * w0.w +
                       (float)hv[4] * w1.x + (float)hv[5] * w1.y +
                       (float)hv[6] * w1.z + (float)hv[7] * w1.w;
            }
            out[(size_t)m * VOCAB + tid] = acc + b_out[tid];
        }
    }
}

// ======================= fallback path (round-1, known good) =======================
#define WIH0_HI 0
#define WIH0_LO (WIH0_HI + HID*EMB)
#define WHH0_HI (WIH0_LO + HID*EMB)
#define WHH0_LO (WHH0_HI + HID*HID)
#define WIH1_HI (WHH0_LO + HID*HID)
#define WIH1_LO (WIH1_HI + HID*HID)
#define WHH1_HI (WIH1_LO + HID*HID)
#define WHH1_LO (WHH1_HI + HID*HID)
#define WOUT_HI (WHH1_LO + HID*HID)
#define WOUT_LO (WOUT_HI + VOCAB*HID)
#define H0_BUF  (WOUT_LO + VOCAB*HID)
#define H1_BUF  (H0_BUF + 2*BATCH*HID)
#define F16_TOTAL (H1_BUF + 2*BATCH*HID)
#define PRE0_BUF 0
#define PRE1_BUF (2*BATCH*HID)

__global__ void split_w(const float* __restrict__ src, _Float16* __restrict__ hi,
                        _Float16* __restrict__ lo, int n) {
    int i = blockIdx.x * blockDim.x + threadIdx.x;
    if (i < n) {
        float v = src[i];
        _Float16 h = (_Float16)v;
        hi[i] = h;
        lo[i] = (_Float16)(v - (float)h);
    }
}

__global__ void zero_h(_Float16* __restrict__ p, int n) {
    int i = blockIdx.x * blockDim.x + threadIdx.x;
    if (i < n) p[i] = (_Float16)0.f;
}

__global__ __launch_bounds__(256) void rnn_step(
    int s,
    const int* __restrict__ tokens, const float* __restrict__ emb,
    const float* __restrict__ b_ih0, const float* __restrict__ b_hh0,
    const float* __restrict__ b_ih1, const float* __restrict__ b_hh1,
    _Float16* __restrict__ wsh, float* __restrict__ wsf)
{
    const int op   = blockIdx.x >> 6;
    const int tile = blockIdx.x & 63;
    const int m0 = (tile >> 4) * 64;
    const int n0 = (tile & 15) * 64;

    int K;
    const _Float16 *A16 = nullptr, *Bhi, *Blo;
    const float *bias, *preadd = nullptr;
    float* out32 = nullptr;
    _Float16* out16 = nullptr;
    bool gather = false;

    switch (op) {
    case 0:
        if (s >= TSEQ) return;
        gather = true; K = EMB;
        Bhi = wsh + WIH0_HI; Blo = wsh + WIH0_LO; bias = b_ih0;
        out32 = wsf + PRE0_BUF + (size_t)(s & 1) * (BATCH * HID);
        break;
    case 1:
        if (s < 1 || s > TSEQ) return;
        A16 = wsh + H0_BUF + (size_t)(s & 1) * (BATCH * HID); K = HID;
        Bhi = wsh + WHH0_HI; Blo = wsh + WHH0_LO; bias = b_hh0;
        preadd = wsf + PRE0_BUF + (size_t)((s - 1) & 1) * (BATCH * HID);
        out16 = wsh + H0_BUF + (size_t)((s - 1) & 1) * (BATCH * HID);
        break;
    case 2:
        if (s < 2 || s > TSEQ + 1) return;
        A16 = wsh + H0_BUF + (size_t)(s & 1) * (BATCH * HID); K = HID;
        Bhi = wsh + WIH1_HI; Blo = wsh + WIH1_LO; bias = b_ih1;
        out32 = wsf + PRE1_BUF + (size_t)(s & 1) * (BATCH * HID);
        break;
    default:
        if (s < 3 || s > TSEQ + 2) return;
        A16 = wsh + H1_BUF + (size_t)(s & 1) * (BATCH * HID); K = HID;
        Bhi = wsh + WHH1_HI; Blo = wsh + WHH1_LO; bias = b_hh1;
        preadd = wsf + PRE1_BUF + (size_t)((s - 1) & 1) * (BATCH * HID);
        out16 = wsh + H1_BUF + (size_t)((s - 1) & 1) * (BATCH * HID);
        break;
    }

    __shared__ _Float16 At[64 * 40];
    __shared__ _Float16 Bth[64 * 40];
    __shared__ _Float16 Btl[64 * 40];

    const int tid  = threadIdx.x;
    const int lane = tid & 63;
    const int wv   = tid >> 6;
    const int wm   = wv & 1;
    const int wn   = wv >> 1;
    const int srow = tid >> 2;
    const int skp  = (tid & 3) * 8;

    f32x4 acc[2][2] = {};

    int tok = 0;
    if (gather) tok = tokens[(m0 + srow) * TSEQ + s];

    for (int k0 = 0; k0 < K; k0 += 32) {
        if (gather) {
            const float* p = emb + (size_t)tok * EMB + k0 + skp;
            float4 u0 = *(const float4*)p;
            float4 u1 = *(const float4*)(p + 4);
            f16x8 a;
            a[0] = (_Float16)u0.x; a[1] = (_Float16)u0.y;
            a[2] = (_Float16)u0.z; a[3] = (_Float16)u0.w;
            a[4] = (_Float16)u1.x; a[5] = (_Float16)u1.y;
            a[6] = (_Float16)u1.z; a[7] = (_Float16)u1.w;
            *(f16x8*)&At[srow * 40 + skp] = a;
        } else {
            *(f16x8*)&At[srow * 40 + skp] =
                *(const f16x8*)(A16 + (size_t)(m0 + srow) * HID + k0 + skp);
        }
        *(f16x8*)&Bth[srow * 40 + skp] =
            *(const f16x8*)(Bhi + (size_t)(n0 + srow) * K + k0 + skp);
        *(f16x8*)&Btl[srow * 40 + skp] =
            *(const f16x8*)(Blo + (size_t)(n0 + srow) * K + k0 + skp);
        __syncthreads();

        const int lr = lane & 15;
        const int lk = (lane >> 4) * 8;
        f16x8 a0  = *(const f16x8*)&At [(wm * 32 +      lr) * 40 + lk];
        f16x8 a1  = *(const f16x8*)&At [(wm * 32 + 16 + lr) * 40 + lk];
        f16x8 bh0 = *(const f16x8*)&Bth[(wn * 32 +      lr) * 40 + lk];
        f16x8 bh1 = *(const f16x8*)&Bth[(wn * 32 + 16 + lr) * 40 + lk];
        f16x8 bl0 = *(const f16x8*)&Btl[(wn * 32 +      lr) * 40 + lk];
        f16x8 bl1 = *(const f16x8*)&Btl[(wn * 32 + 16 + lr) * 40 + lk];

        acc[0][0] = mfma16(a0, bh0, acc[0][0]);
        acc[0][1] = mfma16(a0, bh1, acc[0][1]);
        acc[1][0] = mfma16(a1, bh0, acc[1][0]);
        acc[1][1] = mfma16(a1, bh1, acc[1][1]);
        acc[0][0] = mfma16(a0, bl0, acc[0][0]);
        acc[0][1] = mfma16(a0, bl1, acc[0][1]);
        acc[1][0] = mfma16(a1, bl0, acc[1][0]);
        acc[1][1] = mfma16(a1, bl1, acc[1][1]);
        __syncthreads();
    }

    const int erow = m0 + wm * 32 + (lane >> 4) * 4;
    const int ecol = n0 + wn * 32 + (lane & 15);
    for (int i = 0; i < 2; ++i) {
        for (int j = 0; j < 2; ++j) {
            const int cc = ecol + j * 16;
            const float bv = bias[cc];
            for (int r = 0; r < 4; ++r) {
                const int rr = erow + i * 16 + r;
                float v = acc[i][j][r] + bv;
                if (out16) {
                    v = tanhf(v + preadd[(size_t)rr * HID + cc]);
                    out16[(size_t)rr * HID + cc] = (_Float16)v;
                } else {
                    out32[(size_t)rr * HID + cc] = v;
                }
            }
        }
    }
}

__global__ __launch_bounds__(256) void head_kernel(
    const _Float16* __restrict__ A16,
    const _Float16* __restrict__ Bhi, const _Float16* __restrict__ Blo,
    const float* __restrict__ bias, float* __restrict__ out)
{
    const int m0 = (blockIdx.x >> 1) * 64;
    const int n0 = (blockIdx.x & 1) * 64;
    const int K = HID;

    __shared__ _Float16 At[64 * 40];
    __shared__ _Float16 Bth[64 * 40];
    __shared__ _Float16 Btl[64 * 40];

    const int tid  = threadIdx.x;
    const int lane = tid & 63;
    const int wv   = tid >> 6;
    const int wm   = wv & 1;
    const int wn   = wv >> 1;
    const int srow = tid >> 2;
    const int skp  = (tid & 3) * 8;

    f32x4 acc[2][2] = {};

    for (int k0 = 0; k0 < K; k0 += 32) {
        *(f16x8*)&At[srow * 40 + skp] =
            *(const f16x8*)(A16 + (size_t)(m0 + srow) * HID + k0 + skp);
        *(f16x8*)&Bth[srow * 40 + skp] =
            *(const f16x8*)(Bhi + (size_t)(n0 + srow) * K + k0 + skp);
        *(f16x8*)&Btl[srow * 40 + skp] =
            *(const f16x8*)(Blo + (size_t)(n0 + srow) * K + k0 + skp);
        __syncthreads();

        const int lr = lane & 15;
        const int lk = (lane >> 4) * 8;
        f16x8 a0  = *(const f16x8*)&At [(wm * 32 +      lr) * 40 + lk];
        f16x8 a1  = *(const f16x8*)&At [(wm * 32 + 16 + lr) * 40 + lk];
        f16x8 bh0 = *(const f16x8*)&Bth[(wn * 32 +      lr) * 40 + lk];
        f16x8 bh1 = *(const f16x8*)&Bth[(wn * 32 + 16 + lr) * 40 + lk];
        f16x8 bl0 = *(const f16x8*)&Btl[(wn * 32 +      lr) * 40 + lk];
        f16x8 bl1 = *(const f16x8*)&Btl[(wn * 32 + 16 + lr) * 40 + lk];

        acc[0][0] = mfma16(a0, bh0, acc[0][0]);
        acc[0][1] = mfma16(a0, bh1, acc[0][1]);
        acc[1][0] = mfma16(a1, bh0, acc[1][0]);
        acc[1][1] = mfma16(a1, bh1, acc[1][1]);
        acc[0][0] = mfma16(a0, bl0, acc[0][0]);
        acc[0][1] = mfma16(a0, bl1, acc[0][1]);
        acc[1][0] = mfma16(a1, bl0, acc[1][0]);
        acc[1][1] = mfma16(a1, bl1, acc[1][1]);
        __syncthreads();
    }

    const int erow = m0 + wm * 32 + (lane >> 4) * 4;
    const int ecol = n0 + wn * 32 + (lane & 15);
    for (int i = 0; i < 2; ++i) {
        for (int j = 0; j < 2; ++j) {
            const int cc = ecol + j * 16;
            const float bv = bias[cc];
            for (int r = 0; r < 4; ++r) {
                const int rr = erow + i * 16 + r;
                out[(size_t)rr * VOCAB + cc] = acc[i][j][r] + bv;
            }
        }
    }
}

// ======================= launcher =======================
extern "C" void kernel_launch(void* const* d_in, const int* in_sizes, int n_in,
                              void* d_out, int out_size, void* d_ws, size_t ws_size,
                              hipStream_t stream) {
    const int*   tokens = (const int*)  d_in[0];
    const float* emb    = (const float*)d_in[1];
    const float* W_ih0  = (const float*)d_in[2];
    const float* W_hh0  = (const float*)d_in[3];
    const float* b_ih0  = (const float*)d_in[4];
    const float* b_hh0  = (const float*)d_in[5];
    const float* W_ih1  = (const float*)d_in[6];
    const float* W_hh1  = (const float*)d_in[7];
    const float* b_ih1  = (const float*)d_in[8];
    const float* b_hh1  = (const float*)d_in[9];
    const float* W_out  = (const float*)d_in[10];
    const float* b_out  = (const float*)d_in[11];
    float* out = (float*)d_out;

    // ---- can the persistent cooperative kernel actually launch? ----
    bool coop_ok = false;
    {
        int dev = 0;
        hipGetDevice(&dev);
        int num_cu = 0;
        hipDeviceGetAttribute(&num_cu, hipDeviceAttributeMultiprocessorCount, dev);
        int blocks_per_cu = 0;
        hipError_t oe = hipOccupancyMaxActiveBlocksPerMultiprocessor(
            &blocks_per_cu, (const void*)rnn_persist, 256, 0);
        if (oe == hipSuccess && (long)blocks_per_cu * num_cu >= PGRID)
            coop_ok = true;
        (void)hipGetLastError();  // clear any sticky error
    }

    if (coop_ok) {
        _Float16* wsh = (_Float16*)d_ws;
        float*    wsf = (float*)((char*)d_ws + (size_t)P_F16_TOT * 2);
        void* args[] = {
            (void*)&tokens, (void*)&emb,
            (void*)&W_ih0, (void*)&W_hh0, (void*)&b_ih0, (void*)&b_hh0,
            (void*)&W_ih1, (void*)&W_hh1, (void*)&b_ih1, (void*)&b_hh1,
            (void*)&W_out, (void*)&b_out,
            (void*)&wsh, (void*)&wsf, (void*)&out,
        };
        hipError_t le = hipLaunchCooperativeKernel((const void*)rnn_persist,
                                                   dim3(PGRID), dim3(256),
                                                   args, 0, stream);
        if (le == hipSuccess) return;
        (void)hipGetLastError();  // clear and fall through to fallback
    }

    // ---- fallback: per-step pipeline (round-1, known good) ----
    {
        _Float16* wsh = (_Float16*)d_ws;
        float*    wsf = (float*)((char*)d_ws + (size_t)F16_TOTAL * 2);

        split_w<<<(HID*EMB   + 255) / 256, 256, 0, stream>>>(W_ih0, wsh + WIH0_HI, wsh + WIH0_LO, HID*EMB);
        split_w<<<(HID*HID   + 255) / 256, 256, 0, stream>>>(W_hh0, wsh + WHH0_HI, wsh + WHH0_LO, HID*HID);
        split_w<<<(HID*HID   + 255) / 256, 256, 0, stream>>>(W_ih1, wsh + WIH1_HI, wsh + WIH1_LO, HID*HID);
        split_w<<<(HID*HID   + 255) / 256, 256, 0, stream>>>(W_hh1, wsh + WHH1_HI, wsh + WHH1_LO, HID*HID);
        split_w<<<(VOCAB*HID + 255) / 256, 256, 0, stream>>>(W_out, wsh + WOUT_HI, wsh + WOUT_LO, VOCAB*HID);
        zero_h<<<(4*BATCH*HID + 255) / 256, 256, 0, stream>>>(wsh + H0_BUF, 4*BATCH*HID);

        for (int s = 0; s <= TSEQ + 2; ++s) {
            rnn_step<<<256, 256, 0, stream>>>(s, tokens, emb, b_ih0, b_hh0, b_ih1, b_hh1, wsh, wsf);
        }
        head_kernel<<<8, 256, 0, stream>>>(wsh + H1_BUF + (size_t)BATCH * HID,
                                           wsh + WOUT_HI, wsh + WOUT_LO, b_out, out);
    }
}